// Round 4
// baseline (423.628 us; speedup 1.0000x reference)
//
#include <hip/hip_runtime.h>

#define HH 1024
#define WW 1024
#define NB 16
#define NTH 3
#define BAND 32
#define ACC_BYTES 4096
#define PADC 8            // c9pk left pad
#define C9DIM (PADC + WW + 8)     // 1040
#define PADL 32           // Lf/Lo left pad
#define LDIM (PADL + WW + 2)      // 1058

typedef unsigned int u32;
typedef _Float16 h2 __attribute__((ext_vector_type(2)));

__device__ __forceinline__ u32 pk2(float a, float b){
  h2 h; h[0] = (_Float16)a; h[1] = (_Float16)b;
  u32 r; __builtin_memcpy(&r, &h, 4); return r;
}
__device__ __forceinline__ h2 ash2(u32 v){
  h2 h; __builtin_memcpy(&h, &v, 4); return h;
}
// sigmoid(10*(v-th)) for th = 0, 0.5, 1.0 sharing one exp
__device__ __forceinline__ void sig3(float v, float* sf){
  const float e = __expf(-10.0f * v);
  sf[0] = __fdividef(1.0f, 1.0f + e);
  sf[1] = __fdividef(1.0f, 1.0f + e*148.41315910257660f);
  sf[2] = __fdividef(1.0f, 1.0f + e*22026.465794806718f);
}

__global__ __launch_bounds__(512, 4) void fss_fused(
    const float* __restrict__ F_, const float* __restrict__ O_,
    double* __restrict__ accum)
{
  const int tid = threadIdx.x;
  const int x   = tid << 1;              // base column (even), thread owns x, x+1
  const int ln  = tid & 63, wv = tid >> 6;
  const int y0  = blockIdx.x * BAND;
  const int img = blockIdx.y;
  const float* F = F_ + (size_t)img*HH*WW;
  const float* O = O_ + (size_t)img*HH*WW;

  __shared__ u32            c9pk[2][NTH][C9DIM];
  __shared__ float          Lf  [2][NTH][LDIM];
  __shared__ unsigned short Lo  [2][NTH][LDIM];
  __shared__ float          Tf  [2][NTH][8];
  __shared__ u32            To  [2][NTH][8];
  __shared__ float          redu[8][18];

  { // zero everything once (pads stay zero forever; main regions rewritten per row)
    u32* z1 = &c9pk[0][0][0];
    for (int i = tid; i < 2*NTH*C9DIM; i += 512) z1[i] = 0u;
    float* z2 = &Lf[0][0][0];
    for (int i = tid; i < 2*NTH*LDIM; i += 512) z2[i] = 0.f;
    unsigned short* z3 = &Lo[0][0][0];
    for (int i = tid; i < 2*NTH*LDIM; i += 512) z3[i] = 0;
  }
  __syncthreads();

  float c9f[NTH][2]={{0}}, c9o[NTH][2]={{0}}, c33f[NTH][2]={{0}}, c33o[NTH][2]={{0}};
  float s1d[NTH]={0}, s1r[NTH]={0}, s9d[NTH]={0}, s9r[NTH]={0}, s33d[NTH]={0}, s33r[NTH]={0};

  // ---- warmup: rows [y0-16, y0+16] ----
  #pragma unroll 1
  for (int r = y0-16; r <= y0+16; ++r){
    if ((unsigned)r >= HH) continue;
    const float2 fv = *(const float2*)&F[(size_t)r*WW + x];
    const float2 ov = *(const float2*)&O[(size_t)r*WW + x];
    const bool in9  = (r >= y0-4) && (r <= y0+4);
    const bool ink1 = (r >= y0)   && (r <= y0+4);
    float sf0[3], sf1[3]; sig3(fv.x, sf0); sig3(fv.y, sf1);
    #pragma unroll
    for (int t = 0; t < NTH; ++t){
      const float th = 0.5f*(float)t;
      const float so0 = (ov.x > th) ? 1.f : 0.f, so1 = (ov.y > th) ? 1.f : 0.f;
      c33f[t][0] += sf0[t]; c33f[t][1] += sf1[t];
      c33o[t][0] += so0;    c33o[t][1] += so1;
      if (in9){ c9f[t][0] += sf0[t]; c9f[t][1] += sf1[t];
                c9o[t][0] += so0;    c9o[t][1] += so1; }
      if (ink1){
        const float d0 = sf0[t]-so0, d1 = sf1[t]-so1;
        s1d[t] += d0*d0 + d1*d1;
        s1r[t] += sf0[t]*sf0[t] + so0 + sf1[t]*sf1[t] + so1;   // so^2 == so
      }
    }
  }

  // ---- main loop: 1 barrier per row, parity-buffered LDS ----
  #pragma unroll 2
  for (int y = y0; y < y0 + BAND; ++y){
    const int p = y & 1;

    // P1: publish state centered at row y
    #pragma unroll
    for (int t = 0; t < NTH; ++t){
      uint2 pkw; pkw.x = pk2(c9f[t][0], c9o[t][0]); pkw.y = pk2(c9f[t][1], c9o[t][1]);
      *(uint2*)&c9pk[p][t][PADC + x] = pkw;
      float inf_ = c33f[t][0] + c33f[t][1];
      float ino  = c33o[t][0] + c33o[t][1];
      #pragma unroll
      for (int d = 1; d < 64; d <<= 1){
        const float uf = __shfl_up(inf_, (unsigned)d, 64);
        const float uo = __shfl_up(ino,  (unsigned)d, 64);
        if (ln >= d){ inf_ += uf; ino += uo; }
      }
      float2 lw; lw.x = inf_ - c33f[t][1]; lw.y = inf_;
      *(float2*)&Lf[p][t][PADL + x] = lw;
      const u32 ohi = (u32)(ino + 0.5f);
      const u32 olo = (u32)(ino - c33o[t][1] + 0.5f);
      *(u32*)&Lo[p][t][PADL + x] = (olo & 0xffffu) | (ohi << 16);
      if (ln == 63){ Tf[p][t][wv] = inf_; To[p][t][wv] = ohi; }
    }

    // issue next-row loads early (uniform guards) to overlap the barrier
    const int ri9 = y+5, ro9 = y-4, ri33 = y+17, ro33 = y-16;
    const bool bi9 = (ri9 < HH), bo9 = (ro9 >= 0), bi33 = (ri33 < HH), bo33 = (ro33 >= 0);
    float2 vi9f={0,0}, vi9o={0,0}, vo9f={0,0}, vo9o={0,0};
    float2 vi33f={0,0}, vi33o={0,0}, vo33f={0,0}, vo33o={0,0};
    if (bi9 ){ vi9f  = *(const float2*)&F[(size_t)ri9 *WW + x]; vi9o  = *(const float2*)&O[(size_t)ri9 *WW + x]; }
    if (bo9 ){ vo9f  = *(const float2*)&F[(size_t)ro9 *WW + x]; vo9o  = *(const float2*)&O[(size_t)ro9 *WW + x]; }
    if (bi33){ vi33f = *(const float2*)&F[(size_t)ri33*WW + x]; vi33o = *(const float2*)&O[(size_t)ri33*WW + x]; }
    if (bo33){ vo33f = *(const float2*)&F[(size_t)ro33*WW + x]; vo33o = *(const float2*)&O[(size_t)ro33*WW + x]; }

    __syncthreads();

    // P2: branch-free taps + stats for row y
    const int lo0 = x-17,  lo1 = x-16;
    const int hi0 = min(x+16, WW-1), hi1 = min(x+17, WW-1);
    const int wl0 = max(lo0,0) >> 7, wl1 = max(lo1,0) >> 7;
    const bool m0 = (lo0 >= 0) & ((hi0>>7) != (lo0>>7));
    const bool m1 = (lo1 >= 0) & ((hi1>>7) != (lo1>>7));
    #pragma unroll
    for (int t = 0; t < NTH; ++t){
      // h9 via 5 aligned uint2 reads, sliding for col x+1
      const u32* cb = &c9pk[p][t][PADC + x - 4];
      const uint2 q0 = *(const uint2*)(cb+0);
      const uint2 q1 = *(const uint2*)(cb+2);
      const uint2 q2 = *(const uint2*)(cb+4);
      const uint2 q3 = *(const uint2*)(cb+6);
      const uint2 q4 = *(const uint2*)(cb+8);
      h2 a = ash2(q0.x); a += ash2(q0.y); a += ash2(q1.x); a += ash2(q1.y);
      a += ash2(q2.x); a += ash2(q2.y); a += ash2(q3.x); a += ash2(q3.y);
      a += ash2(q4.x);
      h2 b = a - ash2(q0.x) + ash2(q4.y);
      const float h9f0 = (float)a[0], h9o0 = (float)a[1];
      const float h9f1 = (float)b[0], h9o1 = (float)b[1];

      // h33 via padded wave-local prefixes + masked T-correction
      const float lfl0 = Lf[p][t][PADL+lo0], lfl1 = Lf[p][t][PADL+lo1];
      const float lfh0 = Lf[p][t][PADL+hi0], lfh1 = Lf[p][t][PADL+hi1];
      const int   lol0 = Lo[p][t][PADL+lo0], lol1 = Lo[p][t][PADL+lo1];
      const int   loh0 = Lo[p][t][PADL+hi0], loh1 = Lo[p][t][PADL+hi1];
      const float tf0 = Tf[p][t][wl0], tf1 = Tf[p][t][wl1];
      const int   to0 = (int)To[p][t][wl0], to1 = (int)To[p][t][wl1];
      const float gf0 = lfh0 - lfl0 + (m0 ? tf0 : 0.f);
      const float gf1 = lfh1 - lfl1 + (m1 ? tf1 : 0.f);
      const float go0 = (float)(loh0 - lol0 + (m0 ? to0 : 0));
      const float go1 = (float)(loh1 - lol1 + (m1 ? to1 : 0));

      const float F90 = h9f0*(1.f/81.f), O90 = h9o0*(1.f/81.f);
      const float F91 = h9f1*(1.f/81.f), O91 = h9o1*(1.f/81.f);
      const float d90 = F90-O90, d91 = F91-O91;
      s9d[t] += d90*d90 + d91*d91;
      s9r[t] += F90*F90 + O90*O90 + F91*F91 + O91*O91;
      const float Fa0 = gf0*(1.f/1089.f), Oa0 = go0*(1.f/1089.f);
      const float Fa1 = gf1*(1.f/1089.f), Oa1 = go1*(1.f/1089.f);
      const float da0 = Fa0-Oa0, da1 = Fa1-Oa1;
      s33d[t] += da0*da0 + da1*da1;
      s33r[t] += Fa0*Fa0 + Oa0*Oa0 + Fa1*Fa1 + Oa1*Oa1;
    }

    // P3: slide vertical windows to center y+1 (+ k=1 stats at entering row)
    if (bi9){
      float sf0[3], sf1[3]; sig3(vi9f.x, sf0); sig3(vi9f.y, sf1);
      const bool k1on = (ri9 < y0 + BAND);
      #pragma unroll
      for (int t = 0; t < NTH; ++t){
        const float th = 0.5f*(float)t;
        const float so0 = (vi9o.x > th) ? 1.f : 0.f, so1 = (vi9o.y > th) ? 1.f : 0.f;
        c9f[t][0] += sf0[t]; c9f[t][1] += sf1[t];
        c9o[t][0] += so0;    c9o[t][1] += so1;
        if (k1on){
          const float d0 = sf0[t]-so0, d1 = sf1[t]-so1;
          s1d[t] += d0*d0 + d1*d1;
          s1r[t] += sf0[t]*sf0[t] + so0 + sf1[t]*sf1[t] + so1;
        }
      }
    }
    if (bo9){
      float sf0[3], sf1[3]; sig3(vo9f.x, sf0); sig3(vo9f.y, sf1);
      #pragma unroll
      for (int t = 0; t < NTH; ++t){
        const float th = 0.5f*(float)t;
        const float so0 = (vo9o.x > th) ? 1.f : 0.f, so1 = (vo9o.y > th) ? 1.f : 0.f;
        c9f[t][0] -= sf0[t]; c9f[t][1] -= sf1[t];
        c9o[t][0] -= so0;    c9o[t][1] -= so1;
      }
    }
    if (bi33){
      float sf0[3], sf1[3]; sig3(vi33f.x, sf0); sig3(vi33f.y, sf1);
      #pragma unroll
      for (int t = 0; t < NTH; ++t){
        const float th = 0.5f*(float)t;
        const float so0 = (vi33o.x > th) ? 1.f : 0.f, so1 = (vi33o.y > th) ? 1.f : 0.f;
        c33f[t][0] += sf0[t]; c33f[t][1] += sf1[t];
        c33o[t][0] += so0;    c33o[t][1] += so1;
      }
    }
    if (bo33){
      float sf0[3], sf1[3]; sig3(vo33f.x, sf0); sig3(vo33f.y, sf1);
      #pragma unroll
      for (int t = 0; t < NTH; ++t){
        const float th = 0.5f*(float)t;
        const float so0 = (vo33o.x > th) ? 1.f : 0.f, so1 = (vo33o.y > th) ? 1.f : 0.f;
        c33f[t][0] -= sf0[t]; c33f[t][1] -= sf1[t];
        c33o[t][0] -= so0;    c33o[t][1] -= so1;
      }
    }
  }

  // ---- block reduction: 18 stats -> f64 atomics ----
  #define WRED(v) { _Pragma("unroll") \
    for (int d = 32; d; d >>= 1) v += __shfl_down(v, (unsigned)d, 64); }
  #pragma unroll
  for (int t = 0; t < NTH; ++t){
    WRED(s1d[t]);  WRED(s1r[t]);
    WRED(s9d[t]);  WRED(s9r[t]);
    WRED(s33d[t]); WRED(s33r[t]);
    if (ln == 0){
      redu[wv][t*6+0] = s1d[t];  redu[wv][t*6+1] = s1r[t];
      redu[wv][t*6+2] = s9d[t];  redu[wv][t*6+3] = s9r[t];
      redu[wv][t*6+4] = s33d[t]; redu[wv][t*6+5] = s33r[t];
    }
  }
  __syncthreads();
  if (tid < 18){
    double s = 0.0;
    #pragma unroll
    for (int w = 0; w < 8; ++w) s += (double)redu[w][tid];
    const int t = tid / 6, j = tid % 6;
    atomicAdd(&accum[(size_t)(img*NTH + t)*6 + j], s);
  }
}

__global__ void fss_final(const double* __restrict__ accum, float* __restrict__ out)
{
  if (threadIdx.x == 0 && blockIdx.x == 0){
    const double HW = (double)HH * (double)WW;
    double total = 0.0;
    for (int t = 0; t < NTH; ++t){
      for (int k = 0; k < 3; ++k){
        double s = 0.0;
        for (int img = 0; img < NB; ++img){
          const double* a = accum + (size_t)(img*NTH + t)*6 + (size_t)k*2;
          const double mse  = a[0] / HW;   // stats already in fraction units
          const double mref = a[1] / HW;
          s += 1.0 - mse / (mref + 1e-8);
        }
        total += s / (double)NB;
      }
    }
    out[0] = (float)(1.0 - total/9.0);
  }
}

extern "C" void kernel_launch(void* const* d_in, const int* in_sizes, int n_in,
                              void* d_out, int out_size, void* d_ws, size_t ws_size,
                              hipStream_t stream)
{
  const float* fcst = (const float*)d_in[0];
  const float* obs  = (const float*)d_in[1];
  float* out = (float*)d_out;
  double* accum = (double*)d_ws;

  hipMemsetAsync(d_ws, 0, ACC_BYTES, stream);
  hipLaunchKernelGGL(fss_fused, dim3(HH/BAND, NB), dim3(512), 0, stream,
                     fcst, obs, accum);
  hipLaunchKernelGGL(fss_final, dim3(1), dim3(64), 0, stream, accum, out);
}

// Round 5
// 338.935 us; speedup vs baseline: 1.2499x; 1.2499x over previous
//
#include <hip/hip_runtime.h>

#define HH 1024
#define WW 1024
#define NB 16
#define NTH 3
#define BAND 32
#define ACC_BYTES 4096

#define PADC 8
#define C9DIM  (PADC + WW + 8)    // 1040, taps x-4..x+5
#define PADT 16
#define C33DIM (PADT + WW + 16)   // 1056, taps x-16..x+17
#define P2DIM  520                // index tid+1 <= 512
#define PAD4 8
#define P4DIM  (PAD4 + 512 + 8)   // 528, taps tid-8..tid+6

typedef unsigned int u32;
typedef _Float16 h2 __attribute__((ext_vector_type(2)));

__device__ __forceinline__ u32 pk2(float a, float b){
  h2 h; h[0] = (_Float16)a; h[1] = (_Float16)b;
  u32 r; __builtin_memcpy(&r, &h, 4); return r;
}
__device__ __forceinline__ h2 ash2(u32 v){
  h2 h; __builtin_memcpy(&h, &v, 4); return h;
}
__device__ __forceinline__ u32 hadd(u32 a, u32 b){
  h2 z = ash2(a) + ash2(b);
  u32 r; __builtin_memcpy(&r, &z, 4); return r;
}
// f32 accumulate of one f16 half: v_dot2_f32_f16
__device__ __forceinline__ float fdot(u32 v, h2 sel, float acc){
  return __builtin_amdgcn_fdot2(ash2(v), sel, acc, false);
}
// sigmoid(10*(v-th)) for th = 0, 0.5, 1.0 sharing one exp
__device__ __forceinline__ void sig3(float v, float* sf){
  const float e = __expf(-10.0f * v);
  sf[0] = __fdividef(1.0f, 1.0f + e);
  sf[1] = __fdividef(1.0f, 1.0f + e*148.41315910257660f);
  sf[2] = __fdividef(1.0f, 1.0f + e*22026.465794806718f);
}

__global__ __launch_bounds__(512, 2) void fss_fused(
    const float* __restrict__ F_, const float* __restrict__ O_,
    double* __restrict__ accum)
{
  const int tid = threadIdx.x;
  const int x   = tid << 1;              // base column (even), thread owns x, x+1
  const int ln  = tid & 63, wv = tid >> 6;
  const int y0  = blockIdx.x * BAND;
  const int img = blockIdx.y;
  const float* F = F_ + (size_t)img*HH*WW;
  const float* O = O_ + (size_t)img*HH*WW;

  __shared__ u32   c9pk [2][NTH][C9DIM];
  __shared__ u32   c33pk[2][NTH][C33DIM];
  __shared__ u32   p2arr[NTH][P2DIM];
  __shared__ u32   p4arr[NTH][P4DIM];
  __shared__ float redu[8][18];

  { // zero once: pads stay zero forever; interiors rewritten per row
    u32* z1 = &c9pk[0][0][0];
    for (int i = tid; i < 2*NTH*C9DIM;  i += 512) z1[i] = 0u;
    u32* z2 = &c33pk[0][0][0];
    for (int i = tid; i < 2*NTH*C33DIM; i += 512) z2[i] = 0u;
    u32* z3 = &p2arr[0][0];
    for (int i = tid; i < NTH*P2DIM;    i += 512) z3[i] = 0u;
    u32* z4 = &p4arr[0][0];
    for (int i = tid; i < NTH*P4DIM;    i += 512) z4[i] = 0u;
  }
  __syncthreads();

  float c9f[NTH][2]={{0}}, c9o[NTH][2]={{0}}, c33f[NTH][2]={{0}}, c33o[NTH][2]={{0}};
  float s1d[NTH]={0}, s1r[NTH]={0}, s9d[NTH]={0}, s9r[NTH]={0}, s33d[NTH]={0}, s33r[NTH]={0};

  // ---- warmup: rows [y0-16, y0+16] ----
  #pragma unroll 1
  for (int r = y0-16; r <= y0+16; ++r){
    if ((unsigned)r >= HH) continue;
    const float2 fv = *(const float2*)&F[(size_t)r*WW + x];
    const float2 ov = *(const float2*)&O[(size_t)r*WW + x];
    const bool in9  = (r >= y0-4) && (r <= y0+4);
    const bool ink1 = (r >= y0)   && (r <= y0+4);
    float sf0[3], sf1[3]; sig3(fv.x, sf0); sig3(fv.y, sf1);
    #pragma unroll
    for (int t = 0; t < NTH; ++t){
      const float th = 0.5f*(float)t;
      const float so0 = (ov.x > th) ? 1.f : 0.f, so1 = (ov.y > th) ? 1.f : 0.f;
      c33f[t][0] += sf0[t]; c33f[t][1] += sf1[t];
      c33o[t][0] += so0;    c33o[t][1] += so1;
      if (in9){ c9f[t][0] += sf0[t]; c9f[t][1] += sf1[t];
                c9o[t][0] += so0;    c9o[t][1] += so1; }
      if (ink1){
        const float d0 = sf0[t]-so0, d1 = sf1[t]-so1;
        s1d[t] += d0*d0 + d1*d1;
        s1r[t] += sf0[t]*sf0[t] + so0 + sf1[t]*sf1[t] + so1;   // so^2 == so
      }
    }
  }

  const h2 KF  = { (_Float16) 1.0f, (_Float16) 0.0f };
  const h2 KO  = { (_Float16) 0.0f, (_Float16) 1.0f };
  const h2 KFN = { (_Float16)-1.0f, (_Float16) 0.0f };
  const h2 KON = { (_Float16) 0.0f, (_Float16)-1.0f };

  // ---- main loop: 2 barriers per row, parity-buffered c-arrays ----
  #pragma unroll 2
  for (int y = y0; y < y0 + BAND; ++y){
    const int p = y & 1;
    u32 p2reg[NTH];

    // P1a: publish state centered at row y
    #pragma unroll
    for (int t = 0; t < NTH; ++t){
      uint2 pk9; pk9.x = pk2(c9f[t][0], c9o[t][0]); pk9.y = pk2(c9f[t][1], c9o[t][1]);
      *(uint2*)&c9pk[p][t][PADC + x] = pk9;
      uint2 pk33; pk33.x = pk2(c33f[t][0], c33o[t][0]); pk33.y = pk2(c33f[t][1], c33o[t][1]);
      *(uint2*)&c33pk[p][t][PADT + x] = pk33;
      p2reg[t] = hadd(pk33.x, pk33.y);
      p2arr[t][tid] = p2reg[t];
    }

    // issue next-row loads early (uniform guards) to overlap barriers/LDS phases
    const int ri9 = y+5, ro9 = y-4, ri33 = y+17, ro33 = y-16;
    const bool bi9 = (ri9 < HH), bo9 = (ro9 >= 0), bi33 = (ri33 < HH), bo33 = (ro33 >= 0);
    float2 vi9f={0,0}, vi9o={0,0}, vo9f={0,0}, vo9o={0,0};
    float2 vi33f={0,0}, vi33o={0,0}, vo33f={0,0}, vo33o={0,0};
    if (bi9 ){ vi9f  = *(const float2*)&F[(size_t)ri9 *WW + x]; vi9o  = *(const float2*)&O[(size_t)ri9 *WW + x]; }
    if (bo9 ){ vo9f  = *(const float2*)&F[(size_t)ro9 *WW + x]; vo9o  = *(const float2*)&O[(size_t)ro9 *WW + x]; }
    if (bi33){ vi33f = *(const float2*)&F[(size_t)ri33*WW + x]; vi33o = *(const float2*)&O[(size_t)ri33*WW + x]; }
    if (bo33){ vo33f = *(const float2*)&F[(size_t)ro33*WW + x]; vo33o = *(const float2*)&O[(size_t)ro33*WW + x]; }

    __syncthreads();   // bar1: p2arr visible

    // P1b: build 4-col sums
    #pragma unroll
    for (int t = 0; t < NTH; ++t){
      const u32 nb = p2arr[t][tid+1];
      p4arr[t][PAD4 + tid] = hadd(p2reg[t], nb);
    }
    __syncthreads();   // bar2: p4arr visible

    // P2: taps + stats for row y
    #pragma unroll
    for (int t = 0; t < NTH; ++t){
      // h9 via f16 pk-add chain over 10 packed cols (x-4..x+5)
      const u32* cb = &c9pk[p][t][PADC + x - 4];
      const uint2 q0 = *(const uint2*)(cb+0);
      const uint2 q1 = *(const uint2*)(cb+2);
      const uint2 q2 = *(const uint2*)(cb+4);
      const uint2 q3 = *(const uint2*)(cb+6);
      const uint2 q4 = *(const uint2*)(cb+8);
      h2 a = ash2(q0.x); a += ash2(q0.y); a += ash2(q1.x); a += ash2(q1.y);
      a += ash2(q2.x); a += ash2(q2.y); a += ash2(q3.x); a += ash2(q3.y);
      a += ash2(q4.x);
      const h2 b = a - ash2(q0.x) + ash2(q4.y);
      const float h9f0 = (float)a[0], h9o0 = (float)a[1];
      const float h9f1 = (float)b[0], h9o1 = (float)b[1];

      // h33: 8 aligned p4 taps + 1 c-tap, f32-accumulated via v_dot2_f32_f16
      float gf0 = 0.f, go0 = 0.f;
      #pragma unroll
      for (int k = 0; k < 8; ++k){
        const u32 v = p4arr[t][PAD4 + tid - 8 + 2*k];
        gf0 = fdot(v, KF, gf0); go0 = fdot(v, KO, go0);
      }
      const u32 cP = c33pk[p][t][PADT + x + 16];
      gf0 = fdot(cP, KF, gf0); go0 = fdot(cP, KO, go0);
      const u32 cM = c33pk[p][t][PADT + x - 16];
      const u32 cQ = c33pk[p][t][PADT + x + 17];
      const float gf1 = fdot(cM, KFN, fdot(cQ, KF, gf0));
      const float go1 = fdot(cM, KON, fdot(cQ, KO, go0));

      const float F90 = h9f0*(1.f/81.f), O90 = h9o0*(1.f/81.f);
      const float F91 = h9f1*(1.f/81.f), O91 = h9o1*(1.f/81.f);
      const float d90 = F90-O90, d91 = F91-O91;
      s9d[t] += d90*d90 + d91*d91;
      s9r[t] += F90*F90 + O90*O90 + F91*F91 + O91*O91;
      const float Fa0 = gf0*(1.f/1089.f), Oa0 = go0*(1.f/1089.f);
      const float Fa1 = gf1*(1.f/1089.f), Oa1 = go1*(1.f/1089.f);
      const float da0 = Fa0-Oa0, da1 = Fa1-Oa1;
      s33d[t] += da0*da0 + da1*da1;
      s33r[t] += Fa0*Fa0 + Oa0*Oa0 + Fa1*Fa1 + Oa1*Oa1;
    }

    // P3: slide vertical windows to center y+1 (+ k=1 stats at entering row)
    if (bi9){
      float sf0[3], sf1[3]; sig3(vi9f.x, sf0); sig3(vi9f.y, sf1);
      const bool k1on = (ri9 < y0 + BAND);
      #pragma unroll
      for (int t = 0; t < NTH; ++t){
        const float th = 0.5f*(float)t;
        const float so0 = (vi9o.x > th) ? 1.f : 0.f, so1 = (vi9o.y > th) ? 1.f : 0.f;
        c9f[t][0] += sf0[t]; c9f[t][1] += sf1[t];
        c9o[t][0] += so0;    c9o[t][1] += so1;
        if (k1on){
          const float d0 = sf0[t]-so0, d1 = sf1[t]-so1;
          s1d[t] += d0*d0 + d1*d1;
          s1r[t] += sf0[t]*sf0[t] + so0 + sf1[t]*sf1[t] + so1;
        }
      }
    }
    if (bo9){
      float sf0[3], sf1[3]; sig3(vo9f.x, sf0); sig3(vo9f.y, sf1);
      #pragma unroll
      for (int t = 0; t < NTH; ++t){
        const float th = 0.5f*(float)t;
        const float so0 = (vo9o.x > th) ? 1.f : 0.f, so1 = (vo9o.y > th) ? 1.f : 0.f;
        c9f[t][0] -= sf0[t]; c9f[t][1] -= sf1[t];
        c9o[t][0] -= so0;    c9o[t][1] -= so1;
      }
    }
    if (bi33){
      float sf0[3], sf1[3]; sig3(vi33f.x, sf0); sig3(vi33f.y, sf1);
      #pragma unroll
      for (int t = 0; t < NTH; ++t){
        const float th = 0.5f*(float)t;
        const float so0 = (vi33o.x > th) ? 1.f : 0.f, so1 = (vi33o.y > th) ? 1.f : 0.f;
        c33f[t][0] += sf0[t]; c33f[t][1] += sf1[t];
        c33o[t][0] += so0;    c33o[t][1] += so1;
      }
    }
    if (bo33){
      float sf0[3], sf1[3]; sig3(vo33f.x, sf0); sig3(vo33f.y, sf1);
      #pragma unroll
      for (int t = 0; t < NTH; ++t){
        const float th = 0.5f*(float)t;
        const float so0 = (vo33o.x > th) ? 1.f : 0.f, so1 = (vo33o.y > th) ? 1.f : 0.f;
        c33f[t][0] -= sf0[t]; c33f[t][1] -= sf1[t];
        c33o[t][0] -= so0;    c33o[t][1] -= so1;
      }
    }
  }

  // ---- block reduction: 18 stats -> f64 atomics ----
  #define WRED(v) { _Pragma("unroll") \
    for (int d = 32; d; d >>= 1) v += __shfl_down(v, (unsigned)d, 64); }
  #pragma unroll
  for (int t = 0; t < NTH; ++t){
    WRED(s1d[t]);  WRED(s1r[t]);
    WRED(s9d[t]);  WRED(s9r[t]);
    WRED(s33d[t]); WRED(s33r[t]);
    if (ln == 0){
      redu[wv][t*6+0] = s1d[t];  redu[wv][t*6+1] = s1r[t];
      redu[wv][t*6+2] = s9d[t];  redu[wv][t*6+3] = s9r[t];
      redu[wv][t*6+4] = s33d[t]; redu[wv][t*6+5] = s33r[t];
    }
  }
  __syncthreads();
  if (tid < 18){
    double s = 0.0;
    #pragma unroll
    for (int w = 0; w < 8; ++w) s += (double)redu[w][tid];
    const int t = tid / 6, j = tid % 6;
    atomicAdd(&accum[(size_t)(img*NTH + t)*6 + j], s);
  }
}

__global__ void fss_final(const double* __restrict__ accum, float* __restrict__ out)
{
  if (threadIdx.x == 0 && blockIdx.x == 0){
    const double HW = (double)HH * (double)WW;
    double total = 0.0;
    for (int t = 0; t < NTH; ++t){
      for (int k = 0; k < 3; ++k){
        double s = 0.0;
        for (int img = 0; img < NB; ++img){
          const double* a = accum + (size_t)(img*NTH + t)*6 + (size_t)k*2;
          const double mse  = a[0] / HW;   // stats already in fraction units
          const double mref = a[1] / HW;
          s += 1.0 - mse / (mref + 1e-8);
        }
        total += s / (double)NB;
      }
    }
    out[0] = (float)(1.0 - total/9.0);
  }
}

extern "C" void kernel_launch(void* const* d_in, const int* in_sizes, int n_in,
                              void* d_out, int out_size, void* d_ws, size_t ws_size,
                              hipStream_t stream)
{
  const float* fcst = (const float*)d_in[0];
  const float* obs  = (const float*)d_in[1];
  float* out = (float*)d_out;
  double* accum = (double*)d_ws;

  hipMemsetAsync(d_ws, 0, ACC_BYTES, stream);
  hipLaunchKernelGGL(fss_fused, dim3(HH/BAND, NB), dim3(512), 0, stream,
                     fcst, obs, accum);
  hipLaunchKernelGGL(fss_final, dim3(1), dim3(64), 0, stream, accum, out);
}